// Round 1
// baseline (1360.090 us; speedup 1.0000x reference)
//
#include <hip/hip_runtime.h>
#include <stdint.h>

// SparseMaskHead: sigmoid -> top-k(2500) -> 5x5 dilation -> stable partition by index.
// All outputs written as f32 (harness reads flat f32; indices < 2^24 exact).

namespace {
constexpr int H = 400, W = 400, N = H * W;   // 160000
constexpr int B = 128;
constexpr int NANCH = 2500;
constexpr int NPTS = 20000;
constexpr int POOLCAP = 16384;
constexpr int NB = (N + 1023) / 1024;        // 157 scan blocks of 1024 elems

// output offsets in floats (concat order: out_idx, query_pos, new_mask, xy_vox_idx, ignore_idx)
constexpr long long O_QPOS  = (long long)B * NPTS;                 //  2,560,000
constexpr long long O_NMASK = O_QPOS + (long long)B * 4 * NPTS * 3;// 33,280,000
constexpr long long O_XY    = O_NMASK + (long long)B * N;          // 53,760,000
constexpr long long O_IGN   = O_XY + (long long)B * NPTS * 2;      // 58,880,000
}

__device__ __forceinline__ uint32_t score_key(float x, float m) {
    // matches jax.nn.sigmoid at the top-k boundary region (x>0): 1/(1+exp(-x))
    float e = expf(-x);
    float s = 1.0f / (1.0f + e);
    s *= m;
    return __float_as_uint(s);   // s >= 0 -> bits monotone in value
}

// ---- pass 1: per-batch 64K-bin histogram of key>>16 --------------------------------
__global__ void k_hist(const float* __restrict__ pred, const float* __restrict__ pmask,
                       uint32_t* __restrict__ hist) {
    int b = blockIdx.y;
    int base = blockIdx.x * 2048;
    const float* p = pred + (size_t)b * N;
    const float* m = pmask + (size_t)b * N;
    uint32_t* h = hist + (size_t)b * 65536;
    for (int k = 0; k < 8; ++k) {
        int i = base + k * 256 + threadIdx.x;
        if (i < N) {
            uint32_t key = score_key(p[i], m[i]);
            atomicAdd(&h[key >> 16], 1u);
        }
    }
}

// ---- pass 2: find 16-bit threshold T16 and residual rank R16 per batch -------------
__global__ void k_pick(const uint32_t* __restrict__ hist, uint32_t* __restrict__ T16,
                       int* __restrict__ R16) {
    int b = blockIdx.x;
    const uint32_t* h = hist + (size_t)b * 65536;
    __shared__ uint32_t h8[256];
    int t = threadIdx.x;
    uint32_t s = 0;
    for (int i = 0; i < 256; ++i) s += h[t * 256 + i];
    h8[t] = s;
    __syncthreads();
    if (t == 0) {
        int want = NANCH, acc = 0, hi;
        for (hi = 255; hi >= 0; --hi) {
            int c = (int)h8[hi];
            if (acc + c >= want) break;
            acc += c;
        }
        int wantWithin = want - acc;
        int acc2 = 0, lo;
        for (lo = 255; lo >= 0; --lo) {
            int c = (int)h[hi * 256 + lo];
            if (acc2 + c >= wantWithin) break;
            acc2 += c;
        }
        T16[b] = (uint32_t)(hi * 256 + lo);
        R16[b] = wantWithin - acc2;      // #elems to take from the ==T16 pool, >= 1
    }
}

// ---- pass 3: mark definite anchors (top16 > T16), compact boundary pool ------------
__global__ void k_compact(const float* __restrict__ pred, const float* __restrict__ pmask,
                          const uint32_t* __restrict__ T16, uint8_t* __restrict__ anchor,
                          uint64_t* __restrict__ pool, uint32_t* __restrict__ poolCount) {
    int b = blockIdx.y;
    uint32_t t16 = T16[b];
    int base = blockIdx.x * 2048;
    const float* p = pred + (size_t)b * N;
    const float* m = pmask + (size_t)b * N;
    uint8_t* a = anchor + (size_t)b * N;
    for (int k = 0; k < 8; ++k) {
        int i = base + k * 256 + threadIdx.x;
        if (i < N) {
            uint32_t key = score_key(p[i], m[i]);
            uint32_t top = key >> 16;
            a[i] = (top > t16) ? (uint8_t)1 : (uint8_t)0;
            if (top == t16) {
                uint32_t pos = atomicAdd(&poolCount[b], 1u);
                if (pos < POOLCAP) {
                    // sortable: bigger = better (key desc, index asc)
                    pool[(size_t)b * POOLCAP + pos] =
                        ((uint64_t)(key & 0xFFFFu) << 32) | (uint32_t)(~(uint32_t)i);
                }
            }
        }
    }
}

// ---- pass 4: in-block select of R16 best pool elems (key desc, idx asc) ------------
__global__ void k_pool(const uint64_t* __restrict__ pool, const uint32_t* __restrict__ poolCount,
                       const int* __restrict__ R16, uint8_t* __restrict__ anchor) {
    int b = blockIdx.x;
    int n = min((int)poolCount[b], POOLCAP);
    int R = R16[b];
    const uint64_t* pl = pool + (size_t)b * POOLCAP;
    uint8_t* a = anchor + (size_t)b * N;
    __shared__ uint32_t h[256];
    __shared__ int s_hiB, s_wantB, s_TL, s_wantEq;
    __shared__ uint32_t tieIdx[256];
    __shared__ uint32_t tieCnt;
    __shared__ uint32_t s_tieCut;
    int t = threadIdx.x;
    if (n == 0) return;
    h[t] = 0;
    if (t == 0) tieCnt = 0;
    __syncthreads();
    for (int i = t; i < n; i += 256) {
        uint32_t lo = (uint32_t)(pl[i] >> 32);
        atomicAdd(&h[lo >> 8], 1u);
    }
    __syncthreads();
    if (t == 0) {
        int want = R, acc = 0, hi;
        for (hi = 255; hi >= 0; --hi) { int c = (int)h[hi]; if (acc + c >= want) break; acc += c; }
        s_hiB = hi; s_wantB = want - acc;
    }
    __syncthreads();
    int hiB = s_hiB;
    h[t] = 0;
    __syncthreads();
    for (int i = t; i < n; i += 256) {
        uint32_t lo = (uint32_t)(pl[i] >> 32);
        if ((int)(lo >> 8) == hiB) atomicAdd(&h[lo & 255u], 1u);
    }
    __syncthreads();
    if (t == 0) {
        int want = s_wantB, acc = 0, lo;
        for (lo = 255; lo >= 0; --lo) { int c = (int)h[lo]; if (acc + c >= want) break; acc += c; }
        s_TL = hiB * 256 + lo; s_wantEq = want - acc;
    }
    __syncthreads();
    int TL = s_TL;
    for (int i = t; i < n; i += 256) {
        uint64_t v = pl[i];
        uint32_t lo = (uint32_t)(v >> 32);
        if ((int)lo == TL) {
            uint32_t pos = atomicAdd(&tieCnt, 1u);
            if (pos < 256) tieIdx[pos] = ~((uint32_t)(v & 0xFFFFFFFFull));
        }
    }
    __syncthreads();
    if (t == 0) {
        int cnt = min((int)tieCnt, 256);
        for (int i = 1; i < cnt; ++i) {          // insertion sort asc (tiny)
            uint32_t v = tieIdx[i]; int j = i - 1;
            while (j >= 0 && tieIdx[j] > v) { tieIdx[j + 1] = tieIdx[j]; --j; }
            tieIdx[j + 1] = v;
        }
        int we = s_wantEq; if (we < 1) we = 1; if (we > cnt) we = cnt;
        s_tieCut = tieIdx[we - 1];
    }
    __syncthreads();
    uint32_t tieCut = s_tieCut;
    for (int i = t; i < n; i += 256) {
        uint64_t v = pl[i];
        uint32_t lo = (uint32_t)(v >> 32);
        uint32_t idx = ~((uint32_t)(v & 0xFFFFFFFFull));
        if ((int)lo > TL || ((int)lo == TL && idx <= tieCut)) a[idx] = 1;
    }
}

// ---- pass 5: separable 5x5 dilation (OR) -------------------------------------------
__global__ void k_dilh(const uint8_t* __restrict__ src, uint8_t* __restrict__ dst) {
    int b = blockIdx.y;
    int i = blockIdx.x * 256 + threadIdx.x;
    if (i >= N) return;
    int y = i / W, x = i - y * W;
    const uint8_t* s = src + (size_t)b * N + (size_t)y * W;
    int x0 = max(x - 2, 0), x1 = min(x + 2, W - 1);
    uint8_t v = 0;
    for (int xx = x0; xx <= x1; ++xx) v |= s[xx];
    dst[(size_t)b * N + i] = v;
}

__global__ void k_dilv(const uint8_t* __restrict__ src, uint8_t* __restrict__ dst) {
    int b = blockIdx.y;
    int i = blockIdx.x * 256 + threadIdx.x;
    if (i >= N) return;
    int y = i / W, x = i - y * W;
    const uint8_t* s = src + (size_t)b * N;
    int y0 = max(y - 2, 0), y1 = min(y + 2, H - 1);
    uint8_t v = 0;
    for (int yy = y0; yy <= y1; ++yy) v |= s[(size_t)yy * W + x];
    dst[(size_t)b * N + i] = v ? (uint8_t)1 : (uint8_t)0;
}

// ---- pass 6: prefix scan of dilated mask -------------------------------------------
__global__ void k_bsum(const uint8_t* __restrict__ dil, int* __restrict__ bsum) {
    int b = blockIdx.y, blk = blockIdx.x;
    int base = blk * 1024 + threadIdx.x * 4;
    const uint8_t* d = dil + (size_t)b * N;
    int s = 0;
    if (base + 3 < N) {
        uchar4 v = *reinterpret_cast<const uchar4*>(d + base);
        s = v.x + v.y + v.z + v.w;
    } else {
        for (int k = 0; k < 4; ++k) { int i = base + k; if (i < N) s += d[i]; }
    }
    __shared__ int sh[256];
    sh[threadIdx.x] = s;
    __syncthreads();
    for (int off = 128; off > 0; off >>= 1) {
        if (threadIdx.x < off) sh[threadIdx.x] += sh[threadIdx.x + off];
        __syncthreads();
    }
    if (threadIdx.x == 0) bsum[b * NB + blk] = sh[0];
}

__global__ void k_scan(int* __restrict__ bsum, int* __restrict__ Ttotal) {
    int b = blockIdx.x;
    int* s = bsum + b * NB;
    __shared__ int sh[256];
    int t = threadIdx.x;
    int v = (t < NB) ? s[t] : 0;
    sh[t] = v;
    __syncthreads();
    for (int off = 1; off < 256; off <<= 1) {
        int x = sh[t];
        int y = (t >= off) ? sh[t - off] : 0;
        __syncthreads();
        sh[t] = x + y;
        __syncthreads();
    }
    if (t < NB) s[t] = sh[t] - v;         // exclusive
    if (t == 0) Ttotal[b] = sh[255];      // total trues
}

// ---- pass 7: write all 5 outputs ---------------------------------------------------
__global__ void k_write(const uint8_t* __restrict__ dil, const int* __restrict__ bsumExcl,
                        const int* __restrict__ Ttotal, const float* __restrict__ grid,
                        const float* __restrict__ zs, float* __restrict__ out) {
    int b = blockIdx.y, blk = blockIdx.x, t = threadIdx.x;
    const uint8_t* d = dil + (size_t)b * N;
    int base = blk * 1024 + t * 4;
    int f[4];
    int cnt = 0;
    for (int k = 0; k < 4; ++k) {
        int i = base + k;
        f[k] = (i < N) ? (int)d[i] : 0;
        cnt += f[k];
    }
    __shared__ int sh[256];
    sh[t] = cnt;
    __syncthreads();
    for (int off = 1; off < 256; off <<= 1) {
        int x = sh[t];
        int y = (t >= off) ? sh[t - off] : 0;
        __syncthreads();
        sh[t] = x + y;
        __syncthreads();
    }
    int tr = sh[t] - cnt + bsumExcl[b * NB + blk];   // global #trues before my first elem
    int T = Ttotal[b];
    float z0 = zs[0], z1 = zs[1], z2 = zs[2], z3 = zs[3];
    float* outIdx = out + (size_t)b * NPTS;
    float* qpos   = out + O_QPOS  + (size_t)b * 4 * NPTS * 3;
    float* nmask  = out + O_NMASK + (size_t)b * N;
    float* xy     = out + O_XY    + (size_t)b * NPTS * 2;
    float* ign    = out + O_IGN   + (size_t)b * (N - NPTS);
    for (int k = 0; k < 4; ++k) {
        int i = base + k;
        if (i >= N) break;
        int isT = f[k];
        int orderPos = isT ? tr : (T + (i - tr));
        tr += isT;
        if (orderPos < NPTS) {
            outIdx[orderPos] = (float)i;
            float gx = grid[2 * i], gy = grid[2 * i + 1];
            float* q = qpos + (size_t)orderPos * 3;
            q[0] = gx; q[1] = gy; q[2] = z0;
            q += (size_t)NPTS * 3; q[0] = gx; q[1] = gy; q[2] = z1;
            q += (size_t)NPTS * 3; q[0] = gx; q[1] = gy; q[2] = z2;
            q += (size_t)NPTS * 3; q[0] = gx; q[1] = gy; q[2] = z3;
            nmask[i] = 1.0f;
            xy[2 * orderPos]     = (float)(i / H);   // == row (H==W==400)
            xy[2 * orderPos + 1] = (float)(i % W);   // == col
        } else {
            ign[orderPos - NPTS] = (float)i;
            nmask[i] = 0.0f;
        }
    }
}

extern "C" void kernel_launch(void* const* d_in, const int* in_sizes, int n_in,
                              void* d_out, int out_size, void* d_ws, size_t ws_size,
                              hipStream_t stream) {
    const float* pred  = (const float*)d_in[0];
    const float* pmask = (const float*)d_in[1];
    const float* grid  = (const float*)d_in[2];
    const float* zs    = (const float*)d_in[3];
    float* out = (float*)d_out;

    char* ws = (char*)d_ws;
    uint32_t* hist     = (uint32_t*)ws;                    // 33,554,432 B (reused as dilH)
    uint64_t* pool     = (uint64_t*)(ws + 33554432);       // 16,777,216 B
    uint8_t*  anchor   = (uint8_t*)(ws + 50331648);        // 20,480,000 B (reused as dil)
    int*      bsum     = (int*)(ws + 70811648);            //     80,384 B
    uint32_t* T16      = (uint32_t*)(ws + 70892544);
    int*      R16      = (int*)(ws + 70893056);
    uint32_t* poolCnt  = (uint32_t*)(ws + 70893568);
    int*      Ttotal   = (int*)(ws + 70894080);
    uint8_t*  dilH     = (uint8_t*)ws;                     // alias of hist region (safe: disjoint lifetime)

    hipMemsetAsync(hist, 0, (size_t)B * 65536 * 4, stream);
    hipMemsetAsync(poolCnt, 0, (size_t)B * 4, stream);

    dim3 g1((N + 2047) / 2048, B);   // 79 x 128
    k_hist<<<g1, 256, 0, stream>>>(pred, pmask, hist);
    k_pick<<<B, 256, 0, stream>>>(hist, T16, R16);
    k_compact<<<g1, 256, 0, stream>>>(pred, pmask, T16, anchor, pool, poolCnt);
    k_pool<<<B, 256, 0, stream>>>(pool, poolCnt, R16, anchor);
    dim3 g2((N + 255) / 256, B);     // 625 x 128
    k_dilh<<<g2, 256, 0, stream>>>(anchor, dilH);
    k_dilv<<<g2, 256, 0, stream>>>(dilH, anchor);          // final dil -> anchor buffer
    dim3 g3(NB, B);                  // 157 x 128
    k_bsum<<<g3, 256, 0, stream>>>(anchor, bsum);
    k_scan<<<B, 256, 0, stream>>>(bsum, Ttotal);
    k_write<<<g3, 256, 0, stream>>>(anchor, bsum, Ttotal, grid, zs, out);
}

// Round 2
// 1179.062 us; speedup vs baseline: 1.1535x; 1.1535x over previous
//
#include <hip/hip_runtime.h>
#include <stdint.h>

// SparseMaskHead: sigmoid -> top-k(2500) -> 5x5 dilation -> stable partition by index.
// Round 2: LDS-privatized 2048-bin histogram (kills 410MB of global-atomic write
// traffic), bit-packed masks (13 u32/row), fused bitwise 5x5 dilation, popc scan.

namespace {
constexpr int H = 400, W = 400, N = H * W;   // 160000
constexpr int B = 128;
constexpr int NANCH = 2500;
constexpr int NPTS = 20000;
constexpr int NBINS = 2048;
constexpr int POOLCAP = 16384;
constexpr int WPR = 13;                      // 32-bit words per row (400 bits)
constexpr int NWORDS = H * WPR;              // 5200 words per batch
constexpr int NBW = (NWORDS + 255) / 256;    // 21 word-blocks per batch

// output offsets in floats (concat: out_idx, query_pos, new_mask, xy_vox_idx, ignore_idx)
constexpr long long O_QPOS  = (long long)B * NPTS;                  //  2,560,000
constexpr long long O_NMASK = O_QPOS + (long long)B * 4 * NPTS * 3; // 33,280,000
constexpr long long O_XY    = O_NMASK + (long long)B * N;           // 53,760,000
constexpr long long O_IGN   = O_XY + (long long)B * NPTS * 2;       // 58,880,000
}

__device__ __forceinline__ uint32_t score_key(float x, float m) {
    // matches jax.nn.sigmoid at the top-k boundary (x>0): 1/(1+exp(-x)); s>=0 -> bits monotone
    float e = expf(-x);
    float s = 1.0f / (1.0f + e);
    s *= m;
    return __float_as_uint(s);
}

__device__ __forceinline__ uint32_t key_bin(uint32_t key) {
    // monotone key->bin, fine resolution over s in [0.5, 1.0) where the boundary lives
    if (key >= 0x3F000000u) {
        uint32_t bn = 1024u + ((key - 0x3F000000u) >> 13);  // 1024 bins over [0.5,1)
        return bn > 2047u ? 2047u : bn;                     // s==1.0 clamps into top bin
    }
    return key >> 20;                                       // coarse: 0..1007
}

// ---- pass 1: per-batch 2048-bin histogram, LDS-privatized --------------------------
__global__ void k_hist(const float* __restrict__ pred, const float* __restrict__ pmask,
                       uint32_t* __restrict__ hist) {
    int b = blockIdx.y;
    __shared__ uint32_t lh[NBINS];
    for (int j = threadIdx.x; j < NBINS; j += 256) lh[j] = 0;
    __syncthreads();
    const float* p = pred + (size_t)b * N + blockIdx.x * 20000;
    const float* m = pmask + (size_t)b * N + blockIdx.x * 20000;
    for (int it = 0; it < 20; ++it) {
        int rel = it * 1024 + threadIdx.x * 4;
        if (rel < 20000) {
            float4 pv = *reinterpret_cast<const float4*>(p + rel);
            float4 mv = *reinterpret_cast<const float4*>(m + rel);
            atomicAdd(&lh[key_bin(score_key(pv.x, mv.x))], 1u);
            atomicAdd(&lh[key_bin(score_key(pv.y, mv.y))], 1u);
            atomicAdd(&lh[key_bin(score_key(pv.z, mv.z))], 1u);
            atomicAdd(&lh[key_bin(score_key(pv.w, mv.w))], 1u);
        }
    }
    __syncthreads();
    uint32_t* gh = hist + (size_t)b * NBINS;
    for (int j = threadIdx.x; j < NBINS; j += 256) {
        uint32_t c = lh[j];
        if (c) atomicAdd(&gh[j], c);
    }
}

// ---- pass 2: find threshold bin Tb and residual rank R per batch -------------------
__global__ void k_pick(const uint32_t* __restrict__ hist, int* __restrict__ Tb,
                       int* __restrict__ Rr) {
    int b = blockIdx.x, t = threadIdx.x;
    const uint32_t* h = hist + (size_t)b * NBINS;
    __shared__ uint32_t part[256];
    uint32_t s = 0;
    for (int j = 0; j < 8; ++j) s += h[t * 8 + j];
    part[t] = s;
    __syncthreads();
    if (t == 0) {
        int want = NANCH, acc = 0, c;
        int chunk = 255;
        for (; chunk > 0; --chunk) {
            c = (int)part[chunk];
            if (acc + c >= want) break;
            acc += c;
        }
        int bin = chunk * 8 + 7;
        for (; bin > 0; --bin) {
            c = (int)h[bin];
            if (acc + c >= want) break;
            acc += c;
        }
        Tb[b] = bin;
        Rr[b] = want - acc;   // #elems to take from the ==Tb pool, >= 1
    }
}

// ---- pass 3: definite anchors -> bit words; boundary pool (full key) ---------------
__global__ void k_compact(const float* __restrict__ pred, const float* __restrict__ pmask,
                          const int* __restrict__ Tb, uint32_t* __restrict__ bits,
                          uint64_t* __restrict__ pool, uint32_t* __restrict__ poolCnt) {
    int b = blockIdx.y;
    int w = blockIdx.x * 256 + threadIdx.x;
    if (w >= NWORDS) return;
    int tb = Tb[b];
    int y = w / WPR, k = w - y * WPR;
    int nv = (k == 12) ? 16 : 32;
    int i0 = y * W + k * 32;
    const float* p = pred + (size_t)b * N + i0;
    const float* m = pmask + (size_t)b * N + i0;
    uint32_t word = 0;
    for (int j = 0; j < nv; j += 4) {
        float4 pv = *reinterpret_cast<const float4*>(p + j);
        float4 mv = *reinterpret_cast<const float4*>(m + j);
        float px[4] = {pv.x, pv.y, pv.z, pv.w};
        float mx[4] = {mv.x, mv.y, mv.z, mv.w};
        #pragma unroll
        for (int q = 0; q < 4; ++q) {
            uint32_t key = score_key(px[q], mx[q]);
            int bn = (int)key_bin(key);
            if (bn > tb) {
                word |= (1u << (j + q));
            } else if (bn == tb) {
                uint32_t pos = atomicAdd(&poolCnt[b], 1u);
                if (pos < POOLCAP)
                    pool[(size_t)b * POOLCAP + pos] =
                        ((uint64_t)key << 32) | (uint32_t)(~(uint32_t)(i0 + j + q));
            }
        }
    }
    bits[(size_t)b * NWORDS + w] = word;
}

// ---- pass 4: exact 64-bit radix select of R-th largest pool value ------------------
__global__ void k_pool(const uint64_t* __restrict__ pool, const uint32_t* __restrict__ poolCnt,
                       const int* __restrict__ Rr, uint32_t* __restrict__ bits) {
    int b = blockIdx.x, t = threadIdx.x;
    int n = min((int)poolCnt[b], POOLCAP);
    if (n == 0) return;
    const uint64_t* pl = pool + (size_t)b * POOLCAP;
    __shared__ uint32_t h[256];
    __shared__ uint64_t s_prefix;
    __shared__ int s_R;
    if (t == 0) { s_prefix = 0; s_R = Rr[b]; }
    __syncthreads();
    for (int d = 7; d >= 0; --d) {
        int shf = d * 8;
        h[t] = 0;
        __syncthreads();
        uint64_t pref = s_prefix;
        uint64_t hiMask = (d == 7) ? 0ull : (~0ull << (shf + 8));
        for (int i = t; i < n; i += 256) {
            uint64_t v = pl[i];
            if ((v & hiMask) == pref)
                atomicAdd(&h[(uint32_t)(v >> shf) & 255u], 1u);
        }
        __syncthreads();
        if (t == 0) {
            int R = s_R, acc = 0, bv;
            for (bv = 255; bv > 0; --bv) {
                int c = (int)h[bv];
                if (acc + c >= R) break;
                acc += c;
            }
            s_R = R - acc;
            s_prefix = pref | ((uint64_t)(uint32_t)bv << shf);
        }
        __syncthreads();
    }
    uint64_t vR = s_prefix;   // exact value of R-th largest (values unique via ~idx)
    for (int i = t; i < n; i += 256) {
        uint64_t v = pl[i];
        if (v >= vR) {
            uint32_t idx = ~((uint32_t)(v & 0xFFFFFFFFull));
            int y = idx / W, x = idx - y * W;
            atomicOr(&bits[(size_t)b * NWORDS + y * WPR + (x >> 5)], 1u << (x & 31));
        }
    }
}

// ---- pass 5: fused 5x5 dilation on bit words ---------------------------------------
__global__ void k_dil(const uint32_t* __restrict__ src, uint32_t* __restrict__ dst) {
    int b = blockIdx.y;
    int w = blockIdx.x * 256 + threadIdx.x;
    if (w >= NWORDS) return;
    int y = w / WPR, k = w - y * WPR;
    const uint32_t* s = src + (size_t)b * NWORDS;
    int y0 = max(y - 2, 0), y1 = min(y + 2, H - 1);
    uint32_t acc = 0;
    for (int yy = y0; yy <= y1; ++yy) {
        const uint32_t* row = s + yy * WPR;
        uint32_t c = row[k];
        uint32_t l = (k > 0) ? row[k - 1] : 0u;
        uint32_t r = (k < 12) ? row[k + 1] : 0u;
        acc |= c | (c << 1) | (c << 2) | (c >> 1) | (c >> 2)
             | (l >> 30) | (l >> 31) | (r << 30) | (r << 31);
    }
    if (k == 12) acc &= 0xFFFFu;   // row has 400 valid bits
    dst[(size_t)b * NWORDS + w] = acc;
}

// ---- pass 6: popc block sums + scan -------------------------------------------------
__global__ void k_bsum(const uint32_t* __restrict__ bits, int* __restrict__ bsum) {
    int b = blockIdx.y, blk = blockIdx.x, t = threadIdx.x;
    int w = blk * 256 + t;
    int c = (w < NWORDS) ? __popc(bits[(size_t)b * NWORDS + w]) : 0;
    __shared__ int sh[256];
    sh[t] = c;
    __syncthreads();
    for (int off = 128; off > 0; off >>= 1) {
        if (t < off) sh[t] += sh[t + off];
        __syncthreads();
    }
    if (t == 0) bsum[b * NBW + blk] = sh[0];
}

__global__ void k_scan(int* __restrict__ bsum, int* __restrict__ Ttotal) {
    int b = blockIdx.x, t = threadIdx.x;
    int* s = bsum + b * NBW;
    __shared__ int sh[256];
    int v = (t < NBW) ? s[t] : 0;
    sh[t] = v;
    __syncthreads();
    for (int off = 1; off < 256; off <<= 1) {
        int x = sh[t];
        int yv = (t >= off) ? sh[t - off] : 0;
        __syncthreads();
        sh[t] = x + yv;
        __syncthreads();
    }
    if (t < NBW) s[t] = sh[t] - v;        // exclusive
    if (t == 0) Ttotal[b] = sh[255];      // total trues
}

// ---- pass 7: write all 5 outputs ---------------------------------------------------
__global__ void k_write(const uint32_t* __restrict__ bits, const int* __restrict__ bsumExcl,
                        const int* __restrict__ Ttotal, const float* __restrict__ grid,
                        const float* __restrict__ zs, float* __restrict__ out) {
    int b = blockIdx.y, blk = blockIdx.x, t = threadIdx.x;
    int w = blk * 256 + t;
    uint32_t word = (w < NWORDS) ? bits[(size_t)b * NWORDS + w] : 0u;
    int cnt = __popc(word);
    __shared__ int sh[256];
    sh[t] = cnt;
    __syncthreads();
    for (int off = 1; off < 256; off <<= 1) {
        int x = sh[t];
        int yv = (t >= off) ? sh[t - off] : 0;
        __syncthreads();
        sh[t] = x + yv;
        __syncthreads();
    }
    if (w >= NWORDS) return;
    int tr = sh[t] - cnt + bsumExcl[b * NBW + blk];   // #trues before my first pixel
    int T = Ttotal[b];
    int y = w / WPR, k = w - y * WPR;
    int nv = (k == 12) ? 16 : 32;
    int i0 = y * W + k * 32;
    float z0 = zs[0], z1 = zs[1], z2 = zs[2], z3 = zs[3];
    float* outIdx = out + (size_t)b * NPTS;
    float* qpos   = out + O_QPOS  + (size_t)b * 4 * NPTS * 3;
    float* nmask  = out + O_NMASK + (size_t)b * N;
    float* xy     = out + O_XY    + (size_t)b * NPTS * 2;
    float* ign    = out + O_IGN   + (size_t)b * (N - NPTS);
    for (int j = 0; j < nv; ++j) {
        int i = i0 + j;
        int isT = (int)((word >> j) & 1u);
        int orderPos = isT ? tr : (T + (i - tr));
        tr += isT;
        if (orderPos < NPTS) {
            outIdx[orderPos] = (float)i;
            float gx = grid[2 * i], gy = grid[2 * i + 1];
            float* q = qpos + (size_t)orderPos * 3;
            q[0] = gx; q[1] = gy; q[2] = z0;
            q += (size_t)NPTS * 3; q[0] = gx; q[1] = gy; q[2] = z1;
            q += (size_t)NPTS * 3; q[0] = gx; q[1] = gy; q[2] = z2;
            q += (size_t)NPTS * 3; q[0] = gx; q[1] = gy; q[2] = z3;
            nmask[i] = 1.0f;
            xy[2 * orderPos]     = (float)y;            // i // H  (H==W==400)
            xy[2 * orderPos + 1] = (float)(i - y * W);  // i % W
        } else {
            ign[orderPos - NPTS] = (float)i;
            nmask[i] = 0.0f;
        }
    }
}

extern "C" void kernel_launch(void* const* d_in, const int* in_sizes, int n_in,
                              void* d_out, int out_size, void* d_ws, size_t ws_size,
                              hipStream_t stream) {
    const float* pred  = (const float*)d_in[0];
    const float* pmask = (const float*)d_in[1];
    const float* grid  = (const float*)d_in[2];
    const float* zs    = (const float*)d_in[3];
    float* out = (float*)d_out;

    char* ws = (char*)d_ws;
    uint32_t* hist    = (uint32_t*)ws;                          //  1,048,576 B
    uint64_t* pool    = (uint64_t*)(ws + 1048576);              // 16,777,216 B
    uint32_t* abits   = (uint32_t*)(ws + 17825792);             //  2,662,400 B
    uint32_t* dbits   = (uint32_t*)(ws + 20488192);             //  2,662,400 B
    int*      bsum    = (int*)(ws + 23150592);                  //     10,752 B
    int*      Tb      = (int*)(ws + 23161344);
    int*      Rr      = (int*)(ws + 23161856);
    uint32_t* poolCnt = (uint32_t*)(ws + 23162368);
    int*      Ttotal  = (int*)(ws + 23162880);

    hipMemsetAsync(hist, 0, (size_t)B * NBINS * 4, stream);
    hipMemsetAsync(poolCnt, 0, (size_t)B * 4, stream);

    k_hist<<<dim3(8, B), 256, 0, stream>>>(pred, pmask, hist);
    k_pick<<<B, 256, 0, stream>>>(hist, Tb, Rr);
    dim3 gw(NBW, B);   // 21 x 128
    k_compact<<<gw, 256, 0, stream>>>(pred, pmask, Tb, abits, pool, poolCnt);
    k_pool<<<B, 256, 0, stream>>>(pool, poolCnt, Rr, abits);
    k_dil<<<gw, 256, 0, stream>>>(abits, dbits);
    k_bsum<<<gw, 256, 0, stream>>>(dbits, bsum);
    k_scan<<<B, 256, 0, stream>>>(bsum, Ttotal);
    k_write<<<gw, 256, 0, stream>>>(dbits, bsum, Ttotal, grid, zs, out);
}

// Round 3
// 733.829 us; speedup vs baseline: 1.8534x; 1.6067x over previous
//
#include <hip/hip_runtime.h>
#include <stdint.h>

// SparseMaskHead: sigmoid -> top-k(2500) -> 5x5 dilation -> stable partition by index.
// Round 3: kill the 5x write amplification in k_write (LDS-staged coalesced flush),
// generate qpos/xy in output order (k_qx), LDS-stage k_pick, fuse bsum into dil.

namespace {
constexpr int H = 400, W = 400, N = H * W;   // 160000
constexpr int B = 128;
constexpr int NANCH = 2500;
constexpr int NPTS = 20000;
constexpr int NBINS = 2048;
constexpr int POOLCAP = 16384;
constexpr int WPR = 13;                      // 32-bit words per row (400 bits)
constexpr int NWORDS = H * WPR;              // 5200 words per batch
constexpr int NBW = (NWORDS + 255) / 256;    // 21 word-blocks per batch

// output offsets in floats (concat: out_idx, query_pos, new_mask, xy_vox_idx, ignore_idx)
constexpr long long O_QPOS  = (long long)B * NPTS;                  //  2,560,000
constexpr long long O_NMASK = O_QPOS + (long long)B * 4 * NPTS * 3; // 33,280,000
constexpr long long O_XY    = O_NMASK + (long long)B * N;           // 53,760,000
constexpr long long O_IGN   = O_XY + (long long)B * NPTS * 2;       // 58,880,000
}

__device__ __forceinline__ uint32_t score_key(float x, float m) {
    // matches jax.nn.sigmoid at the top-k boundary (x>0): 1/(1+exp(-x)); s>=0 -> bits monotone
    float e = expf(-x);
    float s = 1.0f / (1.0f + e);
    s *= m;
    return __float_as_uint(s);
}

__device__ __forceinline__ uint32_t key_bin(uint32_t key) {
    // monotone key->bin, fine resolution over s in [0.5, 1.0) where the boundary lives
    if (key >= 0x3F000000u) {
        uint32_t bn = 1024u + ((key - 0x3F000000u) >> 13);  // 1024 bins over [0.5,1)
        return bn > 2047u ? 2047u : bn;                     // s==1.0 clamps into top bin
    }
    return key >> 20;                                       // coarse: 0..1007
}

// ---- pass 1: per-batch 2048-bin histogram, LDS-privatized --------------------------
__global__ void k_hist(const float* __restrict__ pred, const float* __restrict__ pmask,
                       uint32_t* __restrict__ hist) {
    int b = blockIdx.y;
    __shared__ uint32_t lh[NBINS];
    for (int j = threadIdx.x; j < NBINS; j += 256) lh[j] = 0;
    __syncthreads();
    const float* p = pred + (size_t)b * N + blockIdx.x * 20000;
    const float* m = pmask + (size_t)b * N + blockIdx.x * 20000;
    for (int it = 0; it < 20; ++it) {
        int rel = it * 1024 + threadIdx.x * 4;
        if (rel < 20000) {
            float4 pv = *reinterpret_cast<const float4*>(p + rel);
            float4 mv = *reinterpret_cast<const float4*>(m + rel);
            atomicAdd(&lh[key_bin(score_key(pv.x, mv.x))], 1u);
            atomicAdd(&lh[key_bin(score_key(pv.y, mv.y))], 1u);
            atomicAdd(&lh[key_bin(score_key(pv.z, mv.z))], 1u);
            atomicAdd(&lh[key_bin(score_key(pv.w, mv.w))], 1u);
        }
    }
    __syncthreads();
    uint32_t* gh = hist + (size_t)b * NBINS;
    for (int j = threadIdx.x; j < NBINS; j += 256) {
        uint32_t c = lh[j];
        if (c) atomicAdd(&gh[j], c);
    }
}

// ---- pass 2: find threshold bin Tb and residual rank R per batch (LDS-staged) ------
__global__ void k_pick(const uint32_t* __restrict__ hist, int* __restrict__ Tb,
                       int* __restrict__ Rr) {
    int b = blockIdx.x, t = threadIdx.x;
    const uint32_t* h = hist + (size_t)b * NBINS;
    __shared__ uint32_t lh[NBINS];
    __shared__ uint32_t part[256];
    uint32_t s = 0;
    for (int j = 0; j < 8; ++j) {
        uint32_t v = h[t * 8 + j];
        lh[t * 8 + j] = v;
        s += v;
    }
    part[t] = s;
    __syncthreads();
    if (t == 0) {
        int want = NANCH, acc = 0, c;
        int chunk = 255;
        for (; chunk > 0; --chunk) {
            c = (int)part[chunk];
            if (acc + c >= want) break;
            acc += c;
        }
        int bin = chunk * 8 + 7;
        for (; bin > 0; --bin) {
            c = (int)lh[bin];
            if (acc + c >= want) break;
            acc += c;
        }
        Tb[b] = bin;
        Rr[b] = want - acc;   // #elems to take from the ==Tb pool, >= 1
    }
}

// ---- pass 3: definite anchors -> bit words; boundary pool (full key) ---------------
__global__ void k_compact(const float* __restrict__ pred, const float* __restrict__ pmask,
                          const int* __restrict__ Tb, uint32_t* __restrict__ bits,
                          uint64_t* __restrict__ pool, uint32_t* __restrict__ poolCnt) {
    int b = blockIdx.y;
    int w = blockIdx.x * 256 + threadIdx.x;
    if (w >= NWORDS) return;
    int tb = Tb[b];
    int y = w / WPR, k = w - y * WPR;
    int nv = (k == 12) ? 16 : 32;
    int i0 = y * W + k * 32;
    const float* p = pred + (size_t)b * N + i0;
    const float* m = pmask + (size_t)b * N + i0;
    uint32_t word = 0;
    for (int j = 0; j < nv; j += 4) {
        float4 pv = *reinterpret_cast<const float4*>(p + j);
        float4 mv = *reinterpret_cast<const float4*>(m + j);
        float px[4] = {pv.x, pv.y, pv.z, pv.w};
        float mx[4] = {mv.x, mv.y, mv.z, mv.w};
        #pragma unroll
        for (int q = 0; q < 4; ++q) {
            uint32_t key = score_key(px[q], mx[q]);
            int bn = (int)key_bin(key);
            if (bn > tb) {
                word |= (1u << (j + q));
            } else if (bn == tb) {
                uint32_t pos = atomicAdd(&poolCnt[b], 1u);
                if (pos < POOLCAP)
                    pool[(size_t)b * POOLCAP + pos] =
                        ((uint64_t)key << 32) | (uint32_t)(~(uint32_t)(i0 + j + q));
            }
        }
    }
    bits[(size_t)b * NWORDS + w] = word;
}

// ---- pass 4: exact 64-bit radix select of R-th largest pool value ------------------
__global__ void k_pool(const uint64_t* __restrict__ pool, const uint32_t* __restrict__ poolCnt,
                       const int* __restrict__ Rr, uint32_t* __restrict__ bits) {
    int b = blockIdx.x, t = threadIdx.x;
    int n = min((int)poolCnt[b], POOLCAP);
    if (n == 0) return;
    const uint64_t* pl = pool + (size_t)b * POOLCAP;
    __shared__ uint32_t h[256];
    __shared__ uint64_t s_prefix;
    __shared__ int s_R;
    if (t == 0) { s_prefix = 0; s_R = Rr[b]; }
    __syncthreads();
    for (int d = 7; d >= 0; --d) {
        int shf = d * 8;
        h[t] = 0;
        __syncthreads();
        uint64_t pref = s_prefix;
        uint64_t hiMask = (d == 7) ? 0ull : (~0ull << (shf + 8));
        for (int i = t; i < n; i += 256) {
            uint64_t v = pl[i];
            if ((v & hiMask) == pref)
                atomicAdd(&h[(uint32_t)(v >> shf) & 255u], 1u);
        }
        __syncthreads();
        if (t == 0) {
            int R = s_R, acc = 0, bv;
            for (bv = 255; bv > 0; --bv) {
                int c = (int)h[bv];
                if (acc + c >= R) break;
                acc += c;
            }
            s_R = R - acc;
            s_prefix = pref | ((uint64_t)(uint32_t)bv << shf);
        }
        __syncthreads();
    }
    uint64_t vR = s_prefix;   // exact value of R-th largest (values unique via ~idx)
    for (int i = t; i < n; i += 256) {
        uint64_t v = pl[i];
        if (v >= vR) {
            uint32_t idx = ~((uint32_t)(v & 0xFFFFFFFFull));
            int y = idx / W, x = idx - y * W;
            atomicOr(&bits[(size_t)b * NWORDS + y * WPR + (x >> 5)], 1u << (x & 31));
        }
    }
}

// ---- pass 5: fused 5x5 dilation on bit words + block popc sums ---------------------
__global__ void k_dil(const uint32_t* __restrict__ src, uint32_t* __restrict__ dst,
                      int* __restrict__ bsum) {
    int b = blockIdx.y, t = threadIdx.x;
    int w = blockIdx.x * 256 + t;
    uint32_t acc = 0;
    if (w < NWORDS) {
        int y = w / WPR, k = w - y * WPR;
        const uint32_t* s = src + (size_t)b * NWORDS;
        int y0 = max(y - 2, 0), y1 = min(y + 2, H - 1);
        for (int yy = y0; yy <= y1; ++yy) {
            const uint32_t* row = s + yy * WPR;
            uint32_t c = row[k];
            uint32_t l = (k > 0) ? row[k - 1] : 0u;
            uint32_t r = (k < 12) ? row[k + 1] : 0u;
            acc |= c | (c << 1) | (c << 2) | (c >> 1) | (c >> 2)
                 | (l >> 30) | (l >> 31) | (r << 30) | (r << 31);
        }
        if (k == 12) acc &= 0xFFFFu;   // row has 400 valid bits
        dst[(size_t)b * NWORDS + w] = acc;
    }
    __shared__ int sh[256];
    sh[t] = __popc(acc);
    __syncthreads();
    for (int off = 128; off > 0; off >>= 1) {
        if (t < off) sh[t] += sh[t + off];
        __syncthreads();
    }
    if (t == 0) bsum[b * NBW + blockIdx.x] = sh[0];
}

// ---- pass 6: scan of block sums ----------------------------------------------------
__global__ void k_scan(int* __restrict__ bsum, int* __restrict__ Ttotal) {
    int b = blockIdx.x, t = threadIdx.x;
    int* s = bsum + b * NBW;
    __shared__ int sh[256];
    int v = (t < NBW) ? s[t] : 0;
    sh[t] = v;
    __syncthreads();
    for (int off = 1; off < 256; off <<= 1) {
        int x = sh[t];
        int yv = (t >= off) ? sh[t - off] : 0;
        __syncthreads();
        sh[t] = x + yv;
        __syncthreads();
    }
    if (t < NBW) s[t] = sh[t] - v;        // exclusive
    if (t == 0) Ttotal[b] = sh[255];      // total trues
}

// ---- pass 7: out_idx / ignore_idx / new_mask, LDS-staged coalesced flush -----------
__global__ void k_write(const uint32_t* __restrict__ bits, const int* __restrict__ bsumExcl,
                        const int* __restrict__ Ttotal, float* __restrict__ out) {
    int b = blockIdx.y, blk = blockIdx.x, t = threadIdx.x;
    int w = blk * 256 + t;
    uint32_t word = 0;
    int nv = 0, i0 = 0;
    if (w < NWORDS) {
        int y = w / WPR, k = w - y * WPR;
        nv = (k == 12) ? 16 : 32;
        i0 = y * W + k * 32;
        word = bits[(size_t)b * NWORDS + w];
    }
    int cnt = __popc(word);
    int packed = (nv << 16) | cnt;
    __shared__ int sh[256];
    sh[t] = packed;
    __syncthreads();
    for (int off = 1; off < 256; off <<= 1) {
        int x = sh[t];
        int yv = (t >= off) ? sh[t - off] : 0;
        __syncthreads();
        sh[t] = x + yv;
        __syncthreads();
    }
    int exc = sh[t] - packed;
    int truOff = exc & 0xFFFF;          // trues before me in block
    int pixOff = exc >> 16;             // pixels before me in block
    int total = sh[255];
    int blockTrues = total & 0xFFFF;
    int foff = pixOff - truOff;         // falses before me in block
    int blockPix = total >> 16;

    __shared__ uint32_t seg[8192];      // [0,blockTrues): true idxs; rest: false idxs
    {
        int c = 0, f = 0;
        for (int j = 0; j < nv; ++j) {
            uint32_t i = (uint32_t)(i0 + j);
            if ((word >> j) & 1u) seg[truOff + (c++)] = i;
            else                  seg[blockTrues + foff + (f++)] = i;
        }
    }
    // new_mask: contiguous float4 stores
    if (w < NWORDS) {
        float* nm = out + O_NMASK + (size_t)b * N + i0;
        for (int j = 0; j < nv; j += 4) {
            float4 v;
            v.x = (word >> j)       & 1u ? 1.0f : 0.0f;
            v.y = (word >> (j + 1)) & 1u ? 1.0f : 0.0f;
            v.z = (word >> (j + 2)) & 1u ? 1.0f : 0.0f;
            v.w = (word >> (j + 3)) & 1u ? 1.0f : 0.0f;
            *reinterpret_cast<float4*>(nm + j) = v;
        }
    }
    __syncthreads();
    // coalesced flush of the stable partition
    int trBase = bsumExcl[b * NBW + blk];
    int T = Ttotal[b];
    int w0 = blk * 256;
    int pixBefore = (w0 / WPR) * W + (w0 % WPR) * 32;
    int fBaseG = pixBefore - trBase;    // falses before this block, globally
    float* outIdx = out + (size_t)b * NPTS;
    float* ign    = out + O_IGN + (size_t)b * (N - NPTS);
    for (int j = t; j < blockPix; j += 256) {
        uint32_t i = seg[j];
        int op = (j < blockTrues) ? (trBase + j) : (T + fBaseG + (j - blockTrues));
        if (op < NPTS) outIdx[op] = (float)i;
        else           ign[op - NPTS] = (float)i;
    }
}

// ---- pass 8: query_pos + xy_vox_idx in pure output order ---------------------------
__global__ void k_qx(const float* __restrict__ zs, float* __restrict__ out) {
    int b = blockIdx.y;
    int j = blockIdx.x * 256 + threadIdx.x;      // float4 index
    const float* oi = out + (size_t)b * NPTS;    // out_idx (written by k_write)
    if (j < 10000) {
        // xy_vox_idx: float4 = {y0,x0,y1,x1} for points 2j, 2j+1
        int ia = (int)oi[2 * j], ib = (int)oi[2 * j + 1];
        float4 v;
        v.x = (float)(ia / W); v.y = (float)(ia % W);
        v.z = (float)(ib / W); v.w = (float)(ib % W);
        *reinterpret_cast<float4*>(out + O_XY + (size_t)b * NPTS * 2 + 4 * j) = v;
    } else if (j < 70000) {
        int g0 = (j - 10000) * 4;                // flat float index into [4][NPTS][3]
        float vv[4];
        #pragma unroll
        for (int e = 0; e < 4; ++e) {
            int g = g0 + e;
            int p = g / 60000;
            int r = g - p * 60000;
            int pt = r / 3, c = r - pt * 3;
            int i = (int)oi[pt];
            float val;
            if (c == 0)      val = ((float)(i % W) + 0.5f) / 400.0f;  // gx
            else if (c == 1) val = ((float)(i / W) + 0.5f) / 400.0f;  // gy
            else             val = zs[p];
            vv[e] = val;
        }
        *reinterpret_cast<float4*>(out + O_QPOS + (size_t)b * 240000 + g0) =
            make_float4(vv[0], vv[1], vv[2], vv[3]);
    }
}

extern "C" void kernel_launch(void* const* d_in, const int* in_sizes, int n_in,
                              void* d_out, int out_size, void* d_ws, size_t ws_size,
                              hipStream_t stream) {
    const float* pred  = (const float*)d_in[0];
    const float* pmask = (const float*)d_in[1];
    const float* zs    = (const float*)d_in[3];
    float* out = (float*)d_out;

    char* ws = (char*)d_ws;
    uint32_t* hist    = (uint32_t*)ws;                          //  1,048,576 B
    uint64_t* pool    = (uint64_t*)(ws + 1048576);              // 16,777,216 B
    uint32_t* abits   = (uint32_t*)(ws + 17825792);             //  2,662,400 B
    uint32_t* dbits   = (uint32_t*)(ws + 20488192);             //  2,662,400 B
    int*      bsum    = (int*)(ws + 23150592);                  //     10,752 B
    int*      Tb      = (int*)(ws + 23161344);
    int*      Rr      = (int*)(ws + 23161856);
    uint32_t* poolCnt = (uint32_t*)(ws + 23162368);
    int*      Ttotal  = (int*)(ws + 23162880);

    hipMemsetAsync(hist, 0, (size_t)B * NBINS * 4, stream);
    hipMemsetAsync(poolCnt, 0, (size_t)B * 4, stream);

    k_hist<<<dim3(8, B), 256, 0, stream>>>(pred, pmask, hist);
    k_pick<<<B, 256, 0, stream>>>(hist, Tb, Rr);
    dim3 gw(NBW, B);   // 21 x 128
    k_compact<<<gw, 256, 0, stream>>>(pred, pmask, Tb, abits, pool, poolCnt);
    k_pool<<<B, 256, 0, stream>>>(pool, poolCnt, Rr, abits);
    k_dil<<<gw, 256, 0, stream>>>(abits, dbits, bsum);
    k_scan<<<B, 256, 0, stream>>>(bsum, Ttotal);
    k_write<<<gw, 256, 0, stream>>>(dbits, bsum, Ttotal, out);
    k_qx<<<dim3(274, B), 256, 0, stream>>>(zs, out);
}